// Round 5
// baseline (379.864 us; speedup 1.0000x reference)
//
#include <hip/hip_runtime.h>

// Problem: B=65536, S=512, N=514
// Q = M0*...*M513, Mi = I - 2 v_i v_i^T/(v_i^T v_i + eps)
// Compact WY: Q = I - U V^T, U = V R^{-1}, R = striu(G) + diag((G_ii+eps)/2)
// out = x Q^T = x (I - V U^T) = x @ QT,  QT[t][s] = d_ts - sum_i v[i][t] U[s][i]
// QTT[s][t] = QT[t][s] (fp16) is the B^T operand for the MFMA GEMM.
//
// R7 session state: gemm stuck at ~113us across 3 schedules (R3 swizzle-
// grid, R4 T2, R5 T4-counted-vmcnt all ~113; R6 B-direct regressed to 124
// -> reverted to R5 gemm). Delta-total == delta-gemm every round => a
// stable ~248us of NON-gemm time (3 aux kernels, each <113us so never in
// top-5). R7 attacks aux: gram/qtt rebuilt (64x64 tiles, transposed LDS
// stage, ds_read_b128 + 4x4 register tile instead of scalar ds_read_b32
// at 1:1 LDS:FMA), solve gets v_readlane (uniform-lane broadcast, ~5cy)
// replacing __shfl (ds_bpermute ~40cy) inside the 514-long serial chain,
// and 256 blocks x 128 thr (was 128 x 256: half the CUs idle).

#define LDG 520
#define GROWS 528
#define LDU 520
#define NHH 514
#define SDIM 512
#define EPS_HH 1e-16f
#define EPLD 132  // epilogue LDS row stride (floats); 128 was a 4-way ds_write conflict

typedef float f32x4 __attribute__((ext_vector_type(4)));
typedef __fp16 h16x2 __attribute__((ext_vector_type(2)));
typedef __fp16 h16x4v __attribute__((ext_vector_type(4)));
typedef __fp16 h16x8 __attribute__((ext_vector_type(8)));

__device__ __forceinline__ void gl_lds16(const void* g, void* l) {
  __builtin_amdgcn_global_load_lds((const __attribute__((address_space(1))) void*)g,
                                   (__attribute__((address_space(3))) void*)l, 16, 0, 0);
}

// ---------------- Gram: G[i][j] = sum_s v[i][s] v[j][s] ----------------
// 64x64 tile / 256 threads / 4x4 per-thread register tile. LDS stores both
// operands K-transposed (As[k][i]) so the inner loop is 2x ds_read_b128 per
// k (vs 4x scalar ds_read_b32 per k in the old 32x32 version) and 16 FMA.
// Grid 9x9=81 blocks -> single wave of blocks across 256 CUs.
__global__ __launch_bounds__(256) void gram_k(const float* __restrict__ v,
                                              float* __restrict__ G) {
  __shared__ float As[16][68];  // [k][i], +4 pad keeps b128 units 2-way max
  __shared__ float Bs[16][68];  // [k][j]
  const int t = threadIdx.x;
  const int i0 = blockIdx.y * 64, j0 = blockIdx.x * 64;
  const int tx = t & 15, ty = t >> 4;
  const int lr = t & 63, lk = (t >> 6) * 4;  // staging: row, k4 base
  float acc[4][4];
#pragma unroll
  for (int a = 0; a < 4; a++)
#pragma unroll
    for (int b = 0; b < 4; b++) acc[a][b] = 0.f;

  for (int kb = 0; kb < SDIM; kb += 16) {
    __syncthreads();
    float4 av = (i0 + lr < NHH)
                    ? *(const float4*)(v + (size_t)(i0 + lr) * SDIM + kb + lk)
                    : make_float4(0.f, 0.f, 0.f, 0.f);
    float4 bv = (j0 + lr < NHH)
                    ? *(const float4*)(v + (size_t)(j0 + lr) * SDIM + kb + lk)
                    : make_float4(0.f, 0.f, 0.f, 0.f);
    // transposed store: lanes 0..63 hit consecutive banks (conflict-free)
    As[lk + 0][lr] = av.x;
    As[lk + 1][lr] = av.y;
    As[lk + 2][lr] = av.z;
    As[lk + 3][lr] = av.w;
    Bs[lk + 0][lr] = bv.x;
    Bs[lk + 1][lr] = bv.y;
    Bs[lk + 2][lr] = bv.z;
    Bs[lk + 3][lr] = bv.w;
    __syncthreads();
#pragma unroll
    for (int kk = 0; kk < 16; kk++) {
      float4 a4 = *(const float4*)&As[kk][ty * 4];
      float4 b4 = *(const float4*)&Bs[kk][tx * 4];
      float aa[4] = {a4.x, a4.y, a4.z, a4.w};
      float bb[4] = {b4.x, b4.y, b4.z, b4.w};
#pragma unroll
      for (int a = 0; a < 4; a++)
#pragma unroll
        for (int b = 0; b < 4; b++) acc[a][b] = fmaf(aa[a], bb[b], acc[a][b]);
    }
  }
#pragma unroll
  for (int a = 0; a < 4; a++) {
    int row = i0 + ty * 4 + a;
    if (row >= NHH) continue;
#pragma unroll
    for (int b = 0; b < 4; b++) {
      int col = j0 + tx * 4 + b;
      if (col < LDG) G[(size_t)row * LDG + col] = acc[a][b];
    }
  }
}

// ---------------- Solve: U R = V^T-rows, one wave per row s ----------------
// __launch_bounds__(128,1): keep the full VGPR budget for the 8-row G
// prefetch ring (R2: capped bounds spilled the ring -> 120us). R7: 256
// blocks x 2 waves (was 128 x 4): all 256 CUs active, halves per-CU G-read
// bandwidth demand. v_readlane replaces __shfl in the serial chain: the
// broadcast lane sl_ is a compile-time constant and the result is wave-
// uniform, so readlane (SGPR result, ~5cy) beats ds_bpermute (~40cy LDS
// path) on the 514-step dependency chain.
__global__ __launch_bounds__(128, 1) void solve_k(const float* __restrict__ v,
                                                  const float* __restrict__ G,
                                                  float* __restrict__ U) {
  const int lane = threadIdx.x & 63;
  const int s = blockIdx.x * 2 + (threadIdx.x >> 6);
  float W[9];
  float binv[9];
#pragma unroll
  for (int k = 0; k < 9; k++) {
    int j = k * 64 + lane;
    W[k] = (j < NHH) ? v[(size_t)j * SDIM + s] : 0.f;
    binv[k] = (j < NHH) ? (2.0f / (G[(size_t)j * LDG + j] + EPS_HH)) : 0.f;
  }
  float* Urow = U + (size_t)s * LDU;
  float g[8][9];
#pragma unroll
  for (int p = 0; p < 7; p++) {
    const float* gp = G + (size_t)p * LDG + lane;
#pragma unroll
    for (int k = 0; k < 9; k++) g[p][k] = gp[k * 64];
  }
  float usave = 0.f;

  // CI is a compile-time constant (c-loop unrolled) so W[CI]/binv[CI] are
  // direct register refs -- no select chain in the serial dependency path.
#define HH_STEP(I, CI, SLOT, PSLOT, DO_PF)                                 \
  do {                                                                     \
    const int i_ = (I);                                                    \
    if (DO_PF) {                                                           \
      const float* gp_ = G + (size_t)(i_ + 7) * LDG + lane;                \
      _Pragma("unroll") for (int k = 0; k < 9; k++) g[PSLOT][k] =          \
          gp_[k * 64];                                                     \
    }                                                                      \
    const int sl_ = i_ & 63;                                               \
    float u_ = __builtin_bit_cast(                                         \
        float, __builtin_amdgcn_readlane(                                  \
                   __builtin_bit_cast(int, W[CI] * binv[CI]), sl_));       \
    if (lane == sl_) usave = u_;                                           \
    _Pragma("unroll") for (int k = 0; k < 9; k++) W[k] =                   \
        fmaf(-u_, g[SLOT][k], W[k]);                                       \
    if (sl_ == 63) Urow[i_ - 63 + lane] = usave;                           \
  } while (0)

#pragma unroll
  for (int c = 0; c < 8; c++) {
    for (int q = 0; q < 8; q++) {
      const int base = c * 64 + q * 8;
      HH_STEP(base + 0, c, 0, 7, true);
      HH_STEP(base + 1, c, 1, 0, true);
      HH_STEP(base + 2, c, 2, 1, true);
      HH_STEP(base + 3, c, 3, 2, true);
      HH_STEP(base + 4, c, 4, 3, true);
      HH_STEP(base + 5, c, 5, 4, true);
      HH_STEP(base + 6, c, 6, 5, true);
      HH_STEP(base + 7, c, 7, 6, true);
    }
  }
  HH_STEP(512, 8, 0, 0, false);
  HH_STEP(513, 8, 1, 0, false);
  if (lane < 2) Urow[512 + lane] = usave;
#undef HH_STEP
}

// ---------------- QTT[s][t] = delta - sum_i U[s][i] v[i][t]  (fp16) -------
// Same 64x64 / b128 / 4x4 structure as gram_k. K=514 runs as 33 steps of 16
// with per-component masking of U cols >= 514 (removes the old reliance on
// "garbage but finite" U tail values). Output as 8B h16x4 stores.
__global__ __launch_bounds__(256) void qtt_k(const float* __restrict__ v,
                                             const float* __restrict__ U,
                                             __fp16* __restrict__ QTT) {
  __shared__ float As[16][68];  // [k][s] (U transposed)
  __shared__ float Bs[16][68];  // [k][t] (v natural)
  const int t = threadIdx.x;
  const int s0 = blockIdx.y * 64, t0 = blockIdx.x * 64;
  const int tx = t & 15, ty = t >> 4;
  const int lr = t & 63, lk = (t >> 6) * 4;     // U staging: row, k4
  const int brow = t >> 4, bc4 = (t & 15) * 4;  // v staging: k-row, col4
  float acc[4][4];
#pragma unroll
  for (int a = 0; a < 4; a++)
#pragma unroll
    for (int b = 0; b < 4; b++) acc[a][b] = 0.f;

  for (int kb = 0; kb < 528; kb += 16) {
    __syncthreads();
    // U row s0+lr, cols kb+lk..+3. Clamp the address into the row (LDU=520)
    // and zero any component with col >= NHH; clamped loads are fully masked.
    int cl = kb + lk;
    if (cl > 516) cl = 516;
    float4 av = *(const float4*)(U + (size_t)(s0 + lr) * LDU + cl);
    if (kb + lk + 0 >= NHH) av.x = 0.f;
    if (kb + lk + 1 >= NHH) av.y = 0.f;
    if (kb + lk + 2 >= NHH) av.z = 0.f;
    if (kb + lk + 3 >= NHH) av.w = 0.f;
    float4 bv = (kb + brow < NHH)
                    ? *(const float4*)(v + (size_t)(kb + brow) * SDIM + t0 + bc4)
                    : make_float4(0.f, 0.f, 0.f, 0.f);
    As[lk + 0][lr] = av.x;
    As[lk + 1][lr] = av.y;
    As[lk + 2][lr] = av.z;
    As[lk + 3][lr] = av.w;
    *(float4*)&Bs[brow][bc4] = bv;
    __syncthreads();
#pragma unroll
    for (int kk = 0; kk < 16; kk++) {
      float4 a4 = *(const float4*)&As[kk][ty * 4];
      float4 b4 = *(const float4*)&Bs[kk][tx * 4];
      float aa[4] = {a4.x, a4.y, a4.z, a4.w};
      float bb[4] = {b4.x, b4.y, b4.z, b4.w};
#pragma unroll
      for (int a = 0; a < 4; a++)
#pragma unroll
        for (int b = 0; b < 4; b++) acc[a][b] = fmaf(aa[a], bb[b], acc[a][b]);
    }
  }
#pragma unroll
  for (int a = 0; a < 4; a++) {
    int row = s0 + ty * 4 + a;
    h16x4v o;
#pragma unroll
    for (int b = 0; b < 4; b++) {
      int col = t0 + tx * 4 + b;
      o[b] = (__fp16)(((row == col) ? 1.f : 0.f) - acc[a][b]);
    }
    *(h16x4v*)(QTT + (size_t)row * SDIM + t0 + tx * 4) = o;
  }
}

// ---------------- Main GEMM: C[65536x512] = X(f32->f16) @ QTT^T ----------
// R3: XCD-sibling swizzle (FETCH 263->71 MB, confirmed) + 2-phase dbuf.
// R4: T2 XOR-swizzle on LDS tiles (conflicts -50%; dur flat -> hidden).
// R5: T4 counted vmcnt (dur flat; best measured config, 113.3us).
// R6: B-direct-from-global + 4 blocks/CU REGRESSED to 124.5 (L2 latency on
//     the pre-MFMA critical path; occupancy was not the lever) -> reverted
//     to the R5 kernel below, verbatim.
__global__ __launch_bounds__(256) void gemm_k(const float* __restrict__ X,
                                              const __fp16* __restrict__ BT,
                                              float* __restrict__ C) {
  __shared__ __attribute__((aligned(16))) float As[2][128 * 32];
  __shared__ __attribute__((aligned(16))) __fp16 Bs[2][128 * 32];
  const int t = threadIdx.x;
  const int lane = t & 63, wave = t >> 6;
  // bid -> (m,n): xcd = bid&7; g = bid>>3; n = g&3; m = (g>>2)*8 + xcd.
  // Siblings (m fixed, n=0..3) are bids xcd + 8*(4*(g>>2)+n): delta 8 apart.
  const int bid = blockIdx.x;
  const int xcd = bid & 7;
  const int g = bid >> 3;
  const int m0 = ((g >> 2) * 8 + xcd) * 128;
  const int n0 = (g & 3) * 128;
  const int wm = (wave >> 1) * 64, wn = (wave & 1) * 64;
  const int rr = lane & 15, kg = lane >> 4;
  const int wb = t & ~63;  // wave-uniform thread base

  f32x4 acc[4][4];
#pragma unroll
  for (int a = 0; a < 4; a++)
#pragma unroll
    for (int b = 0; b < 4; b++) acc[a][b] = (f32x4){0.f, 0.f, 0.f, 0.f};

  // Stage one 128x32 A tile (f32, 16 KB, 4 issues) + 128x32 B tile (f16,
  // 8 KB, 2 issues) into LDS buffer `buf`. LDS dest is wave-uniform base +
  // lane*16 (global_load_lds constraint, LINEAR); the bank swizzle is
  // realized by permuting the per-lane GLOBAL source column-unit.
  auto STAGE = [&](int k0, int buf) {
#pragma unroll
    for (int q = 0; q < 4; q++) {
      int idx = q * 256 + t;
      int r = idx >> 3, u = idx & 7;           // row, 16B-unit within row
      int c = (u ^ (r & 7)) * 4;               // swizzled source col (floats)
      const float* gp = X + (size_t)(m0 + r) * 512 + k0 + c;
      gl_lds16(gp, (void*)&As[buf][(size_t)(q * 256 + wb) * 4]);
    }
#pragma unroll
    for (int q = 0; q < 2; q++) {
      int idx = q * 256 + t;
      int r = idx >> 2, u = idx & 3;
      int c = (u ^ (r & 3)) * 8;               // swizzled source col (fp16)
      const __fp16* gp = BT + (size_t)(n0 + r) * 512 + k0 + c;
      gl_lds16(gp, (void*)&Bs[buf][(size_t)(q * 256 + wb) * 8]);
    }
  };

  STAGE(0, 0);  // 6 loads in flight for buf 0; NOT drained here.

  const int swzA = rr & 7;  // == (A row & 7) for every row this lane reads
  const int swzB = rr & 3;  // == (B row & 3)

  for (int ks = 0; ks < 16; ++ks) {
    const int cur = ks & 1;
    if (ks < 15) {
      // Issue next tile's 6 loads (-> buf cur^1, safe: all waves passed the
      // previous iteration's trailing barrier, done reading cur^1).
      STAGE((ks + 1) * 32, cur ^ 1);
      // Wait only for the 6 OLDEST loads (targeting cur, issued one full
      // iteration ago); the 6 just issued stay in flight across the barrier.
      asm volatile("s_waitcnt vmcnt(6)" ::: "memory");
    } else {
      asm volatile("s_waitcnt vmcnt(0)" ::: "memory");
    }
    // All waves' staging for cur is LDS-visible once every wave passed its
    // own vmcnt wait and this barrier.
    asm volatile("s_barrier" ::: "memory");

    h16x8 af[4], bf[4];
#pragma unroll
    for (int mi = 0; mi < 4; mi++) {
      const float* rowp = &As[cur][(size_t)(wm + mi * 16 + rr) * 32];
      float4 lo = *(const float4*)(rowp + (size_t)((2 * kg + 0) ^ swzA) * 4);
      float4 hi = *(const float4*)(rowp + (size_t)((2 * kg + 1) ^ swzA) * 4);
      h16x2 p0 = __builtin_amdgcn_cvt_pkrtz(lo.x, lo.y);
      h16x2 p1 = __builtin_amdgcn_cvt_pkrtz(lo.z, lo.w);
      h16x2 p2 = __builtin_amdgcn_cvt_pkrtz(hi.x, hi.y);
      h16x2 p3 = __builtin_amdgcn_cvt_pkrtz(hi.z, hi.w);
      h16x8 a = {p0[0], p0[1], p1[0], p1[1], p2[0], p2[1], p3[0], p3[1]};
      af[mi] = a;
    }
#pragma unroll
    for (int ni = 0; ni < 4; ni++) {
      const __fp16* rowp = &Bs[cur][(size_t)(wn + ni * 16 + rr) * 32];
      bf[ni] = *(const h16x8*)(rowp + (size_t)(kg ^ swzB) * 8);
    }

#pragma unroll
    for (int mi = 0; mi < 4; mi++)
#pragma unroll
      for (int ni = 0; ni < 4; ni++)
        acc[mi][ni] =
            __builtin_amdgcn_mfma_f32_16x16x32_f16(af[mi], bf[ni], acc[mi][ni], 0, 0, 0);

    // Trailing barrier: no vmcnt drain. Protects buf cur (just read) from
    // iteration ks+1's STAGE DMA. ds_reads above already completed (their
    // results were consumed by MFMA under compiler-inserted lgkmcnt).
    asm volatile("s_barrier" ::: "memory");
  }

  // Epilogue via LDS: full-128B-line float4 stores (R2: scalar dword stores
  // correlated with +131 MB FETCH == C-size -> suspected RMW line fills).
  // Row stride EPLD=132: ds_write pattern is 2-way (free) instead of 4-way.
  float* Ep = (float*)As;  // 2 bufs x 16 rows x 132 cols = 16.9 KB < 32 KB
  const int lr = (lane >> 4) * 4;
  const int lc = wn + rr;
  const int buf = wave >> 1;
#pragma unroll
  for (int rnd = 0; rnd < 4; rnd++) {
    float* bp = Ep + buf * (16 * EPLD);
#pragma unroll
    for (int ni = 0; ni < 4; ni++)
#pragma unroll
      for (int q = 0; q < 4; q++)
        bp[(lr + q) * EPLD + lc + ni * 16] = acc[rnd][ni][q];
    __syncthreads();
#pragma unroll
    for (int j = 0; j < 4; j++) {
      int fidx = j * 256 + t;      // 0..1023 float4s
      int b = fidx >> 9;           // which buf (0: rows wm=0, 1: rows wm=64)
      int wi = fidx & 511;
      int lrow = wi >> 5;
      int c4 = wi & 31;
      int grow = m0 + b * 64 + rnd * 16 + lrow;
      *(float4*)(C + (size_t)grow * 512 + n0 + c4 * 4) =
          *(const float4*)(Ep + b * (16 * EPLD) + lrow * EPLD + c4 * 4);
    }
    __syncthreads();
  }
}

extern "C" void kernel_launch(void* const* d_in, const int* in_sizes, int n_in,
                              void* d_out, int out_size, void* d_ws, size_t ws_size,
                              hipStream_t stream) {
  const float* x = (const float*)d_in[0];        // [65536][512] f32
  const float* v = (const float*)d_in[1];        // [514][512] f32
  float* out = (float*)d_out;                    // [65536][512] f32

  char* w = (char*)d_ws;
  float* G = (float*)w;                                   // 528*520*4 = 1,098,240 B
  float* U = (float*)(w + (size_t)GROWS * LDG * 4);       // 512*520*4 = 1,064,960 B
  __fp16* QTT =
      (__fp16*)(w + (size_t)GROWS * LDG * 4 + (size_t)512 * LDU * 4);  // 512 KB

  gram_k<<<dim3(9, 9), 256, 0, stream>>>(v, G);
  solve_k<<<256, 128, 0, stream>>>(v, G, U);
  qtt_k<<<dim3(8, 8), 256, 0, stream>>>(v, U, QTT);
  gemm_k<<<2048, 256, 0, stream>>>(x, QTT, out);
}